// Round 4
// baseline (212.556 us; speedup 1.0000x reference)
//
#include <hip/hip_runtime.h>

// GlobalAttention fused kernel for MI355X — round 4.
// alpha = softmax(V·w_v + hid_term)  [hid_term drops: softmax shift-invariance]
// attn  = sum_p alpha_p V[p,:] ;  out = relu([inp, attn] @ ctx_w^T + ctx_b)
// Single pass over V (134 MB). Round-4 deltas vs round-3:
//   k1: 512-thr blocks (32 waves/CU, deeper load queue)  [was 16 waves/CU]
//   k2: coalesced two-stage column reduce                [was 2052B-stride reads]

#define HDIM 512
#define NPOS 65536   // 256*256
#define B1   1024    // k1 blocks (also partial count)
#define W1   (B1*8)  // total k1 waves
#define NITER (NPOS / W1)   // 8 rows per wave

__device__ __forceinline__ float wave_sum(float v) {
#pragma unroll
    for (int m = 32; m >= 1; m >>= 1) v += __shfl_xor(v, m, 64);
    return v;
}

// K1: per-block partial of (sum_p exp(alpha_p)*V[p][k], sum_p exp(alpha_p)).
// ws1: [B1][513]  (k<512 = weighted V partial, k=512 = exp-sum partial)
__global__ __launch_bounds__(512, 8)
void k1_partial(const float* __restrict__ V, const float* __restrict__ att_w,
                float* __restrict__ ws1) {
    const int tid  = threadIdx.x;
    const int lane = tid & 63;
    const int wid  = tid >> 6;              // 0..7
    const int gw   = blockIdx.x * 8 + wid;  // global wave id, 0..8191

    // lane owns k = lane*8 .. lane*8+7 of every row
    const float* wvp = att_w + HDIM + lane * 8;
    const float4 wv0 = *reinterpret_cast<const float4*>(wvp);
    const float4 wv1 = *reinterpret_cast<const float4*>(wvp + 4);

    float acc[8] = {0.f,0.f,0.f,0.f,0.f,0.f,0.f,0.f};
    float lsum = 0.f;

#pragma unroll 2
    for (int it = 0; it < NITER; ++it) {
        const int p = gw + it * W1;         // wave-coalesced 2KB rows
        const float* vp = V + (size_t)p * HDIM + lane * 8;
        const float4 a0 = *reinterpret_cast<const float4*>(vp);
        const float4 a1 = *reinterpret_cast<const float4*>(vp + 4);
        float d = a0.x*wv0.x + a0.y*wv0.y + a0.z*wv0.z + a0.w*wv0.w;
        d      += a1.x*wv1.x + a1.y*wv1.y + a1.z*wv1.z + a1.w*wv1.w;
        d = wave_sum(d);
        const float e = __expf(d);          // |alpha| ~ 2: no max-shift needed
        lsum += e;
        acc[0] += e*a0.x; acc[1] += e*a0.y; acc[2] += e*a0.z; acc[3] += e*a0.w;
        acc[4] += e*a1.x; acc[5] += e*a1.y; acc[6] += e*a1.z; acc[7] += e*a1.w;
    }

    __shared__ float lds[8][HDIM];
    __shared__ float ldsl[8];
    float4* lv = reinterpret_cast<float4*>(&lds[wid][lane * 8]);
    lv[0] = make_float4(acc[0], acc[1], acc[2], acc[3]);
    lv[1] = make_float4(acc[4], acc[5], acc[6], acc[7]);
    if (lane == 0) ldsl[wid] = lsum;        // wave-uniform
    __syncthreads();

    float s = 0.f;
#pragma unroll
    for (int w = 0; w < 8; ++w) s += lds[w][tid];
    float* dst = ws1 + (size_t)blockIdx.x * 513;
    dst[tid] = s;                           // coalesced: tid==k, 512 cols
    if (tid == 0) {
        float t = 0.f;
#pragma unroll
        for (int w = 0; w < 8; ++w) t += ldsl[w];
        dst[512] = t;
    }
}

// K2a: reduce 1024 partials -> 64, coalesced (thread t reads col t / t+256).
__global__ __launch_bounds__(256)
void k2a(const float* __restrict__ ws1, float* __restrict__ ws1b) {
    const int g = blockIdx.x;               // 0..63, owns rows g*16..g*16+15
    const int t = threadIdx.x;
    const float* base = ws1 + (size_t)g * 16 * 513;
#pragma unroll
    for (int half = 0; half < 2; ++half) {
        const int c = t + half * 256;
        float s = 0.f;
#pragma unroll
        for (int r = 0; r < 16; ++r) s += base[r * 513 + c];
        ws1b[g * 513 + c] = s;
    }
    if (t == 0) {
        float s = 0.f;
#pragma unroll
        for (int r = 0; r < 16; ++r) s += base[r * 513 + 512];
        ws1b[g * 513 + 512] = s;
    }
}

// K2b: 64 -> 1 final combine. ws2[0..511] = raw attn, ws2[512] = L.
__global__ __launch_bounds__(256)
void k2b(const float* __restrict__ ws1b, float* __restrict__ ws2) {
    const int t = threadIdx.x;
#pragma unroll
    for (int half = 0; half < 2; ++half) {
        const int c = t + half * 256;
        float s = 0.f;
#pragma unroll
        for (int g = 0; g < 64; ++g) s += ws1b[g * 513 + c];
        ws2[c] = s;
    }
    if (t == 0) {
        float s = 0.f;
#pragma unroll
        for (int g = 0; g < 64; ++g) s += ws1b[g * 513 + 512];
        ws2[512] = s;
    }
}

// K3: out[r] = relu( dot(cat, ctx_w[r]) + ctx_b[r] ), cat = [inp, attn_raw/L]
__global__ __launch_bounds__(256)
void k3_fc(const float* __restrict__ inp, const float* __restrict__ ctx_w,
           const float* __restrict__ ctx_b, const float* __restrict__ ws2,
           float* __restrict__ out) {
    const int lane = threadIdx.x & 63;
    const int wid  = threadIdx.x >> 6;
    const int r = blockIdx.x * 4 + wid;     // 0..511
    const float invL = 1.0f / ws2[512];
    const int cbase = lane * 16;            // lane covers 16 of 1024 cols

    float4 c0, c1, c2, c3;
    if (lane < 32) {                        // c < 512: inp
        const float* p = inp + cbase;
        c0 = *reinterpret_cast<const float4*>(p);
        c1 = *reinterpret_cast<const float4*>(p + 4);
        c2 = *reinterpret_cast<const float4*>(p + 8);
        c3 = *reinterpret_cast<const float4*>(p + 12);
    } else {                                // c >= 512: attn = raw/L
        const float* p = ws2 + (cbase - HDIM);
        c0 = *reinterpret_cast<const float4*>(p);
        c1 = *reinterpret_cast<const float4*>(p + 4);
        c2 = *reinterpret_cast<const float4*>(p + 8);
        c3 = *reinterpret_cast<const float4*>(p + 12);
        c0.x *= invL; c0.y *= invL; c0.z *= invL; c0.w *= invL;
        c1.x *= invL; c1.y *= invL; c1.z *= invL; c1.w *= invL;
        c2.x *= invL; c2.y *= invL; c2.z *= invL; c2.w *= invL;
        c3.x *= invL; c3.y *= invL; c3.z *= invL; c3.w *= invL;
    }

    const float* w = ctx_w + (size_t)r * 1024 + cbase;
    const float4 w0 = *reinterpret_cast<const float4*>(w);
    const float4 w1 = *reinterpret_cast<const float4*>(w + 4);
    const float4 w2 = *reinterpret_cast<const float4*>(w + 8);
    const float4 w3 = *reinterpret_cast<const float4*>(w + 12);

    float d = c0.x*w0.x + c0.y*w0.y + c0.z*w0.z + c0.w*w0.w;
    d      += c1.x*w1.x + c1.y*w1.y + c1.z*w1.z + c1.w*w1.w;
    d      += c2.x*w2.x + c2.y*w2.y + c2.z*w2.z + c2.w*w2.w;
    d      += c3.x*w3.x + c3.y*w3.y + c3.z*w3.z + c3.w*w3.w;
    d = wave_sum(d);
    if (lane == 0) out[r] = fmaxf(d + ctx_b[r], 0.0f);
}

extern "C" void kernel_launch(void* const* d_in, const int* in_sizes, int n_in,
                              void* d_out, int out_size, void* d_ws, size_t ws_size,
                              hipStream_t stream) {
    const float* inp   = (const float*)d_in[0];
    // d_in[1] = hid   : unused (softmax shift-invariance)
    const float* V     = (const float*)d_in[2];
    const float* att_w = (const float*)d_in[3];
    // d_in[4] = att_b : unused (softmax shift-invariance)
    const float* ctx_w = (const float*)d_in[5];
    const float* ctx_b = (const float*)d_in[6];
    float* out = (float*)d_out;
    float* ws  = (float*)d_ws;

    float* ws1  = ws;                              // [1024][513]
    float* ws1b = ws1 + (size_t)B1 * 513;          // [64][513]
    float* ws2  = ws1b + (size_t)64 * 513;         // [513]

    k1_partial<<<dim3(B1), dim3(512), 0, stream>>>(V, att_w, ws1);
    k2a       <<<dim3(64), dim3(256), 0, stream>>>(ws1, ws1b);
    k2b       <<<dim3(1),  dim3(256), 0, stream>>>(ws1b, ws2);
    k3_fc     <<<dim3(128),dim3(256), 0, stream>>>(inp, ctx_w, ctx_b, ws2, out);
}

// Round 8
// 208.348 us; speedup vs baseline: 1.0202x; 1.0202x over previous
//
#include <hip/hip_runtime.h>

// GlobalAttention fused kernel for MI355X — round 5 design (resubmitted; rounds
// 5-7 benches were GPUAcquisitionTimeouts, never measured).
// alpha = softmax(V·w_v + hid_term)  [hid_term drops: softmax shift-invariance]
// attn  = sum_p alpha_p V[p,:] ;  out = relu([inp, attn] @ ctx_w^T + ctx_b)
// Single pass over V (134 MB, BW-bound; verified occupancy-insensitive r3/r4).
// Deltas vs r4: 3 launches (k2b fused into k3), B1 1024->512 (half the
// partial traffic). k1 inner loop untouched.

#define HDIM 512
#define NPOS 65536            // 256*256
#define B1   512              // k1 blocks == partial rows
#define W1   (B1*8)           // total k1 waves (512 blocks x 8 waves)
#define NITER (NPOS / W1)     // 16 rows per wave
#define NB2  64               // stage-2 partial rows

__device__ __forceinline__ float wave_sum(float v) {
#pragma unroll
    for (int m = 32; m >= 1; m >>= 1) v += __shfl_xor(v, m, 64);
    return v;
}

// K1: per-block partial of (sum_p exp(alpha_p)*V[p][k], sum_p exp(alpha_p)).
// ws1: [B1][513]  (k<512 = weighted V partial, k=512 = exp-sum partial)
__global__ __launch_bounds__(512, 8)
void k1_partial(const float* __restrict__ V, const float* __restrict__ att_w,
                float* __restrict__ ws1) {
    const int tid  = threadIdx.x;
    const int lane = tid & 63;
    const int wid  = tid >> 6;              // 0..7
    const int gw   = blockIdx.x * 8 + wid;  // global wave id, 0..4095

    // lane owns k = lane*8 .. lane*8+7 of every row
    const float* wvp = att_w + HDIM + lane * 8;
    const float4 wv0 = *reinterpret_cast<const float4*>(wvp);
    const float4 wv1 = *reinterpret_cast<const float4*>(wvp + 4);

    float acc[8] = {0.f,0.f,0.f,0.f,0.f,0.f,0.f,0.f};
    float lsum = 0.f;

#pragma unroll 2
    for (int it = 0; it < NITER; ++it) {
        const int p = gw + it * W1;         // wave-coalesced 2KB rows
        const float* vp = V + (size_t)p * HDIM + lane * 8;
        const float4 a0 = *reinterpret_cast<const float4*>(vp);
        const float4 a1 = *reinterpret_cast<const float4*>(vp + 4);
        float d = a0.x*wv0.x + a0.y*wv0.y + a0.z*wv0.z + a0.w*wv0.w;
        d      += a1.x*wv1.x + a1.y*wv1.y + a1.z*wv1.z + a1.w*wv1.w;
        d = wave_sum(d);
        const float e = __expf(d);          // |alpha| ~ 2: no max-shift needed
        lsum += e;
        acc[0] += e*a0.x; acc[1] += e*a0.y; acc[2] += e*a0.z; acc[3] += e*a0.w;
        acc[4] += e*a1.x; acc[5] += e*a1.y; acc[6] += e*a1.z; acc[7] += e*a1.w;
    }

    __shared__ float lds[8][HDIM];
    __shared__ float ldsl[8];
    float4* lv = reinterpret_cast<float4*>(&lds[wid][lane * 8]);
    lv[0] = make_float4(acc[0], acc[1], acc[2], acc[3]);
    lv[1] = make_float4(acc[4], acc[5], acc[6], acc[7]);
    if (lane == 0) ldsl[wid] = lsum;        // wave-uniform
    __syncthreads();

    float s = 0.f;
#pragma unroll
    for (int w = 0; w < 8; ++w) s += lds[w][tid];
    float* dst = ws1 + (size_t)blockIdx.x * 513;
    dst[tid] = s;                           // coalesced: tid==k
    if (tid == 0) {
        float t = 0.f;
#pragma unroll
        for (int w = 0; w < 8; ++w) t += ldsl[w];
        dst[512] = t;
    }
}

// K2a: reduce 512 partials -> 64, fully coalesced per row.
__global__ __launch_bounds__(256)
void k2a(const float* __restrict__ ws1, float* __restrict__ ws1b) {
    const int g = blockIdx.x;               // 0..63, owns rows g*8..g*8+7
    const int t = threadIdx.x;
    const float* base = ws1 + (size_t)g * 8 * 513;
#pragma unroll
    for (int half = 0; half < 2; ++half) {
        const int c = t + half * 256;
        float s = 0.f;
#pragma unroll
        for (int r = 0; r < 8; ++r) s += base[r * 513 + c];
        ws1b[g * 513 + c] = s;
    }
    if (t == 0) {
        float s = 0.f;
#pragma unroll
        for (int r = 0; r < 8; ++r) s += base[r * 513 + 512];
        ws1b[g * 513 + 512] = s;
    }
}

// K3 (fused final combine + FC):
// each block reduces ws1b[64][513] (L2-hot, coalesced) into LDS, then
// out[r] = relu( dot([inp, attn/L], ctx_w[r]) + ctx_b[r] ) for its 4 rows.
__global__ __launch_bounds__(256)
void k3_fc(const float* __restrict__ inp, const float* __restrict__ ctx_w,
           const float* __restrict__ ctx_b, const float* __restrict__ ws1b,
           float* __restrict__ out) {
    __shared__ float att[HDIM];             // attn raw (un-normalized)
    __shared__ float Lsh;
    const int t = threadIdx.x;

#pragma unroll
    for (int half = 0; half < 2; ++half) {
        const int c = t + half * 256;
        float s = 0.f;
#pragma unroll
        for (int g = 0; g < NB2; ++g) s += ws1b[g * 513 + c];
        att[c] = s;
    }
    if (t == 0) {
        float s = 0.f;
#pragma unroll
        for (int g = 0; g < NB2; ++g) s += ws1b[g * 513 + 512];
        Lsh = s;
    }
    __syncthreads();

    const int lane = t & 63;
    const int wid  = t >> 6;
    const int r = blockIdx.x * 4 + wid;     // 0..511
    const float invL = 1.0f / Lsh;
    const int cbase = lane * 16;            // lane covers 16 of 1024 cols

    float4 c0, c1, c2, c3;
    if (lane < 32) {                        // c < 512: inp
        const float* p = inp + cbase;
        c0 = *reinterpret_cast<const float4*>(p);
        c1 = *reinterpret_cast<const float4*>(p + 4);
        c2 = *reinterpret_cast<const float4*>(p + 8);
        c3 = *reinterpret_cast<const float4*>(p + 12);
    } else {                                // c >= 512: attn = raw/L (from LDS)
        const float* p = att + (cbase - HDIM);
        c0 = make_float4(p[0]*invL,  p[1]*invL,  p[2]*invL,  p[3]*invL);
        c1 = make_float4(p[4]*invL,  p[5]*invL,  p[6]*invL,  p[7]*invL);
        c2 = make_float4(p[8]*invL,  p[9]*invL,  p[10]*invL, p[11]*invL);
        c3 = make_float4(p[12]*invL, p[13]*invL, p[14]*invL, p[15]*invL);
    }

    const float* w = ctx_w + (size_t)r * 1024 + cbase;
    const float4 w0 = *reinterpret_cast<const float4*>(w);
    const float4 w1 = *reinterpret_cast<const float4*>(w + 4);
    const float4 w2 = *reinterpret_cast<const float4*>(w + 8);
    const float4 w3 = *reinterpret_cast<const float4*>(w + 12);

    float d = c0.x*w0.x + c0.y*w0.y + c0.z*w0.z + c0.w*w0.w;
    d      += c1.x*w1.x + c1.y*w1.y + c1.z*w1.z + c1.w*w1.w;
    d      += c2.x*w2.x + c2.y*w2.y + c2.z*w2.z + c2.w*w2.w;
    d      += c3.x*w3.x + c3.y*w3.y + c3.z*w3.z + c3.w*w3.w;
    d = wave_sum(d);
    if (lane == 0) out[r] = fmaxf(d + ctx_b[r], 0.0f);
}

extern "C" void kernel_launch(void* const* d_in, const int* in_sizes, int n_in,
                              void* d_out, int out_size, void* d_ws, size_t ws_size,
                              hipStream_t stream) {
    const float* inp   = (const float*)d_in[0];
    // d_in[1] = hid   : unused (softmax shift-invariance)
    const float* V     = (const float*)d_in[2];
    const float* att_w = (const float*)d_in[3];
    // d_in[4] = att_b : unused (softmax shift-invariance)
    const float* ctx_w = (const float*)d_in[5];
    const float* ctx_b = (const float*)d_in[6];
    float* out = (float*)d_out;
    float* ws  = (float*)d_ws;

    float* ws1  = ws;                              // [512][513]
    float* ws1b = ws1 + (size_t)B1 * 513;          // [64][513]

    k1_partial<<<dim3(B1),  dim3(512), 0, stream>>>(V, att_w, ws1);
    k2a       <<<dim3(NB2), dim3(256), 0, stream>>>(ws1, ws1b);
    k3_fc     <<<dim3(128), dim3(256), 0, stream>>>(inp, ctx_w, ctx_b, ws1b, out);
}